// Round 3
// baseline (463.436 us; speedup 1.0000x reference)
//
#include <hip/hip_runtime.h>

#define HIDDEN 1024
#define BATCH 32
#define SEQ 2048
#define NCHUNK 16
#define CHUNK 128  // SEQ / NCHUNK

__device__ __forceinline__ float wave_sum(float v) {
#pragma unroll
    for (int off = 32; off > 0; off >>= 1) v += __shfl_xor(v, off, 64);
    return v;
}

__device__ __forceinline__ float dot4(float4 a, float4 b) {
    return a.x * b.x + a.y * b.y + a.z * b.z + a.w * b.w;
}

// y[b][d] = dot(W[d,:], vin[b*vstride : +H]) + bias[d].  One wave per (b,d).
__global__ __launch_bounds__(256) void k_matvec(const float* __restrict__ W,
                                                const float* __restrict__ vin,
                                                size_t vstride,
                                                const float* __restrict__ bias,
                                                float* __restrict__ y) {
    int wave = blockIdx.x * 4 + (threadIdx.x >> 6);
    int lane = threadIdx.x & 63;
    int b = wave >> 10;
    int d = wave & 1023;
    const float* vr = vin + (size_t)b * vstride;
    const float* wr = W + ((size_t)d << 10);
    float acc = 0.f;
#pragma unroll
    for (int j = 0; j < 4; ++j)
        acc += dot4(*(const float4*)(vr + j * 256 + lane * 4),
                    *(const float4*)(wr + j * 256 + lane * 4));
    acc = wave_sum(acc);
    if (lane == 0) y[wave] = acc + bias[d];
}

// c[b] = (q[b] . bk) / 32.  One wave per b.
__global__ __launch_bounds__(64) void k_c(const float* __restrict__ q,
                                          const float* __restrict__ bk,
                                          float* __restrict__ c) {
    int b = blockIdx.x;
    int lane = threadIdx.x;
    const float* qr = q + (b << 10);
    float acc = 0.f;
#pragma unroll
    for (int j = 0; j < 4; ++j)
        acc += dot4(*(const float4*)(qr + j * 256 + lane * 4),
                    *(const float4*)(bk + j * 256 + lane * 4));
    acc = wave_sum(acc);
    if (lane == 0) c[b] = acc * (1.0f / 32.0f);
}

// qk[b][h] = (sum_d Wk[d][h] * q[b][d]) / 32   (Wk^T q, coalesced over h)
__global__ __launch_bounds__(256) void k_qk(const float* __restrict__ Wk,
                                            const float* __restrict__ q,
                                            float* __restrict__ qk) {
    int b = blockIdx.x >> 2;
    int h = ((blockIdx.x & 3) << 8) | threadIdx.x;
    const float* qr = q + (b << 10);
    float acc = 0.f;
#pragma unroll 8
    for (int d = 0; d < HIDDEN; ++d)
        acc = fmaf(Wk[((size_t)d << 10) | h], qr[d], acc);
    qk[(b << 10) | h] = acc * (1.0f / 32.0f);
}

// Fused flash-style pass: scores + online softmax + weighted-x accumulation.
// One block per (b, s-chunk of 128 rows). 4 waves, each wave owns rows wid+4i.
__global__ __launch_bounds__(256) void k_attn(const float* __restrict__ x,
                                              const float* __restrict__ qk,
                                              const float* __restrict__ cb,
                                              float* __restrict__ scores,   // raw scores -> d_out weights area
                                              float* __restrict__ bacc,     // [B*NCHUNK][HIDDEN]
                                              float* __restrict__ bml) {    // [B*NCHUNK][2] = (m, l)
    int blk = blockIdx.x;
    int b = blk >> 4;
    int s0 = (blk & 15) * CHUNK;
    int wid = threadIdx.x >> 6, lane = threadIdx.x & 63;

    const float* qkr = qk + (b << 10);
    float4 qv[4];
#pragma unroll
    for (int j = 0; j < 4; ++j) qv[j] = *(const float4*)(qkr + j * 256 + lane * 4);
    float cbv = cb[b];

    float m = -1e30f, l = 0.f;
    float4 acc[4];
#pragma unroll
    for (int j = 0; j < 4; ++j) acc[j] = make_float4(0.f, 0.f, 0.f, 0.f);

    for (int i = 0; i < CHUNK / 4; ++i) {
        int s = s0 + (i << 2) + wid;
        const float* xr = x + ((size_t)b * SEQ + s) * HIDDEN;
        float4 xv[4];
#pragma unroll
        for (int j = 0; j < 4; ++j) xv[j] = *(const float4*)(xr + j * 256 + lane * 4);
        float dt = 0.f;
#pragma unroll
        for (int j = 0; j < 4; ++j) dt += dot4(xv[j], qv[j]);
        float sc = wave_sum(dt) + cbv;
        if (lane == 0) scores[b * SEQ + s] = sc;
        float mn = fmaxf(m, sc);
        float f = __expf(m - mn);
        float p = __expf(sc - mn);
        l = l * f + p;
#pragma unroll
        for (int j = 0; j < 4; ++j) {
            acc[j].x = acc[j].x * f + p * xv[j].x;
            acc[j].y = acc[j].y * f + p * xv[j].y;
            acc[j].z = acc[j].z * f + p * xv[j].z;
            acc[j].w = acc[j].w * f + p * xv[j].w;
        }
        m = mn;
    }

    // combine the 4 waves
    __shared__ float sacc[4][HIDDEN];
    __shared__ float sm[4], sl[4];
#pragma unroll
    for (int j = 0; j < 4; ++j)
        *(float4*)&sacc[wid][j * 256 + lane * 4] = acc[j];
    if (lane == 0) { sm[wid] = m; sl[wid] = l; }
    __syncthreads();
    float M = fmaxf(fmaxf(sm[0], sm[1]), fmaxf(sm[2], sm[3]));
    float f0 = __expf(sm[0] - M), f1 = __expf(sm[1] - M);
    float f2 = __expf(sm[2] - M), f3 = __expf(sm[3] - M);
    float L = sl[0] * f0 + sl[1] * f1 + sl[2] * f2 + sl[3] * f3;
    int h = threadIdx.x << 2;
    float4 a0 = *(const float4*)&sacc[0][h];
    float4 a1 = *(const float4*)&sacc[1][h];
    float4 a2 = *(const float4*)&sacc[2][h];
    float4 a3 = *(const float4*)&sacc[3][h];
    float4 r;
    r.x = a0.x * f0 + a1.x * f1 + a2.x * f2 + a3.x * f3;
    r.y = a0.y * f0 + a1.y * f1 + a2.y * f2 + a3.y * f3;
    r.z = a0.z * f0 + a1.z * f1 + a2.z * f2 + a3.z * f3;
    r.w = a0.w * f0 + a1.w * f1 + a2.w * f2 + a3.w * f3;
    *(float4*)&bacc[((size_t)blk << 10) + h] = r;
    if (threadIdx.x == 0) { bml[blk * 2] = M; bml[blk * 2 + 1] = L; }
}

// Per-batch combine: global (M,L), xb[b] = sum_i f_i*acc_i / L, normalize weights.
__global__ __launch_bounds__(256) void k_finalize(const float* __restrict__ bacc,
                                                  const float* __restrict__ bml,
                                                  float* __restrict__ weights,
                                                  float* __restrict__ xb) {
    int b = blockIdx.x;
    float M = -1e30f;
#pragma unroll
    for (int i = 0; i < NCHUNK; ++i) M = fmaxf(M, bml[(b * NCHUNK + i) * 2]);
    float fs[NCHUNK];
    float L = 0.f;
#pragma unroll
    for (int i = 0; i < NCHUNK; ++i) {
        fs[i] = __expf(bml[(b * NCHUNK + i) * 2] - M);
        L += fs[i] * bml[(b * NCHUNK + i) * 2 + 1];
    }
    float invL = 1.f / L;
    int h = threadIdx.x << 2;
    float4 r = make_float4(0.f, 0.f, 0.f, 0.f);
#pragma unroll
    for (int i = 0; i < NCHUNK; ++i) {
        float4 a = *(const float4*)&bacc[((size_t)(b * NCHUNK + i) << 10) + h];
        float f = fs[i] * invL;
        r.x += f * a.x; r.y += f * a.y; r.z += f * a.z; r.w += f * a.w;
    }
    *(float4*)&xb[(b << 10) + h] = r;
#pragma unroll
    for (int i = 0; i < SEQ / 256; ++i) {
        int s = threadIdx.x + i * 256;
        float sc = weights[b * SEQ + s];
        weights[b * SEQ + s] = __expf(sc - M) * invL;
    }
}

extern "C" void kernel_launch(void* const* d_in, const int* in_sizes, int n_in,
                              void* d_out, int out_size, void* d_ws, size_t ws_size,
                              hipStream_t stream) {
    const float* x  = (const float*)d_in[0];
    const float* Wq = (const float*)d_in[1];
    const float* bq = (const float*)d_in[2];
    const float* Wk = (const float*)d_in[3];
    const float* bk = (const float*)d_in[4];
    const float* Wv = (const float*)d_in[5];
    const float* bv = (const float*)d_in[6];

    float* out = (float*)d_out;
    float* ctx = out;                        // [B][H]
    float* wts = out + BATCH * HIDDEN;       // [B][S]

    float* ws   = (float*)d_ws;
    float* q    = ws;                        // B*H
    float* qk   = q + BATCH * HIDDEN;        // B*H
    float* cb   = qk + BATCH * HIDDEN;       // B (padded to 64)
    float* xb   = cb + 64;                   // B*H
    float* bml  = xb + BATCH * HIDDEN;       // B*NCHUNK*2
    float* bacc = bml + 2 * BATCH * NCHUNK;  // B*NCHUNK*H  (2 MiB)

    // q[b] = Wq x_last[b] + bq
    k_matvec<<<dim3((BATCH * HIDDEN) / 4), dim3(256), 0, stream>>>(
        Wq, x + (size_t)(SEQ - 1) * HIDDEN, (size_t)SEQ * HIDDEN, bq, q);
    // c[b] = q.bk / 32
    k_c<<<dim3(BATCH), dim3(64), 0, stream>>>(q, bk, cb);
    // qk[b] = Wk^T q[b] / 32
    k_qk<<<dim3(BATCH * 4), dim3(256), 0, stream>>>(Wk, q, qk);
    // single pass over x: scores + online-softmax weighted accumulation
    k_attn<<<dim3(BATCH * NCHUNK), dim3(256), 0, stream>>>(x, qk, cb, wts, bacc, bml);
    // combine per-batch, write normalized weights + xb
    k_finalize<<<dim3(BATCH), dim3(256), 0, stream>>>(bacc, bml, wts, xb);
    // context[b] = Wv xb[b] + bv
    k_matvec<<<dim3((BATCH * HIDDEN) / 4), dim3(256), 0, stream>>>(
        Wv, xb, (size_t)HIDDEN, bv, ctx);
}

// Round 7
// 428.441 us; speedup vs baseline: 1.0817x; 1.0817x over previous
//
#include <hip/hip_runtime.h>

#define HIDDEN 1024
#define BATCH 32
#define SEQ 2048
#define NCHUNK 64
#define CHUNK 32  // SEQ / NCHUNK

__device__ __forceinline__ float wave_sum(float v) {
#pragma unroll
    for (int off = 32; off > 0; off >>= 1) v += __shfl_xor(v, off, 64);
    return v;
}

__device__ __forceinline__ float dot4(float4 a, float4 b) {
    return a.x * b.x + a.y * b.y + a.z * b.z + a.w * b.w;
}

// y[b][d] = dot(W[d,:], vin[b*vstride : +H]) + bias[d].  One wave per (b,d).
__global__ __launch_bounds__(256) void k_matvec(const float* __restrict__ W,
                                                const float* __restrict__ vin,
                                                size_t vstride,
                                                const float* __restrict__ bias,
                                                float* __restrict__ y) {
    int wave = blockIdx.x * 4 + (threadIdx.x >> 6);
    int lane = threadIdx.x & 63;
    int b = wave >> 10;
    int d = wave & 1023;
    const float* vr = vin + (size_t)b * vstride;
    const float* wr = W + ((size_t)d << 10);
    float acc = 0.f;
#pragma unroll
    for (int j = 0; j < 4; ++j)
        acc += dot4(*(const float4*)(vr + j * 256 + lane * 4),
                    *(const float4*)(wr + j * 256 + lane * 4));
    acc = wave_sum(acc);
    if (lane == 0) y[wave] = acc + bias[d];
}

// c[b] = (q[b] . bk) / 32.  One wave per b.
__global__ __launch_bounds__(64) void k_c(const float* __restrict__ q,
                                          const float* __restrict__ bk,
                                          float* __restrict__ c) {
    int b = blockIdx.x;
    int lane = threadIdx.x;
    const float* qr = q + (b << 10);
    float acc = 0.f;
#pragma unroll
    for (int j = 0; j < 4; ++j)
        acc += dot4(*(const float4*)(qr + j * 256 + lane * 4),
                    *(const float4*)(bk + j * 256 + lane * 4));
    acc = wave_sum(acc);
    if (lane == 0) c[b] = acc * (1.0f / 32.0f);
}

// qk[b][h] = (sum_d Wk[d][h] * q[b][d]) / 32.  Block = 1024 threads:
// h = tid&255 (within the block's 256-h slab), dc = tid>>8 splits the d-loop
// 4 ways (16 waves/block for latency hiding); LDS combine at the end.
__global__ __launch_bounds__(1024) void k_qk(const float* __restrict__ Wk,
                                             const float* __restrict__ q,
                                             float* __restrict__ qk) {
    int b = blockIdx.x >> 2;
    int hlo = threadIdx.x & 255;
    int h = ((blockIdx.x & 3) << 8) | hlo;
    int dc = threadIdx.x >> 8;  // 0..3
    const float* qr = q + (b << 10) + (dc << 8);
    const float* wp = Wk + (((size_t)dc << 8) << 10) + h;
    float a0 = 0.f, a1 = 0.f;
#pragma unroll 4
    for (int d = 0; d < 256; d += 2) {
        a0 = fmaf(wp[(size_t)d << 10], qr[d], a0);
        a1 = fmaf(wp[(size_t)(d + 1) << 10], qr[d + 1], a1);
    }
    __shared__ float red[4][256];
    red[dc][hlo] = a0 + a1;
    __syncthreads();
    if (threadIdx.x < 256) {
        float s = red[0][threadIdx.x] + red[1][threadIdx.x] +
                  red[2][threadIdx.x] + red[3][threadIdx.x];
        qk[(b << 10) | h] = s * (1.0f / 32.0f);
    }
}

// Fused flash-style pass: scores + online softmax + weighted-x accumulation.
// One block per (b, s-chunk of 32 rows). 4 waves; wave wid owns rows wid+4i.
// Row loads are double-buffered so iteration i+1's HBM load overlaps i's compute.
__global__ __launch_bounds__(256) void k_attn(const float* __restrict__ x,
                                              const float* __restrict__ qk,
                                              const float* __restrict__ cb,
                                              float* __restrict__ scores,   // raw scores -> d_out weights area
                                              float* __restrict__ bacc,     // [B*NCHUNK][HIDDEN]
                                              float* __restrict__ bml) {    // [B*NCHUNK][2] = (m, l)
    int blk = blockIdx.x;
    int b = blk >> 6;
    int s0 = (blk & 63) * CHUNK;
    int wid = threadIdx.x >> 6, lane = threadIdx.x & 63;

    const float* qkr = qk + (b << 10);
    float4 qv[4];
#pragma unroll
    for (int j = 0; j < 4; ++j) qv[j] = *(const float4*)(qkr + j * 256 + lane * 4);
    float cbv = cb[b];

    float m = -1e30f, l = 0.f;
    float4 acc[4];
#pragma unroll
    for (int j = 0; j < 4; ++j) acc[j] = make_float4(0.f, 0.f, 0.f, 0.f);

    // base row for this wave: s0 + wid, stride 4 rows per iteration, 8 iterations
    const float* xr = x + ((size_t)b * SEQ + s0 + wid) * HIDDEN + lane * 4;

    float4 bufA[4], bufB[4];
#pragma unroll
    for (int j = 0; j < 4; ++j) bufA[j] = *(const float4*)(xr + j * 256);

    auto step = [&](float4 (&cur)[4], float4 (&nxt)[4], int i) {
        if (i < 7) {
            const float* xn = xr + (size_t)(i + 1) * 4 * HIDDEN;
#pragma unroll
            for (int j = 0; j < 4; ++j) nxt[j] = *(const float4*)(xn + j * 256);
        }
        float dt = 0.f;
#pragma unroll
        for (int j = 0; j < 4; ++j) dt += dot4(cur[j], qv[j]);
        float sc = wave_sum(dt) + cbv;
        if (lane == 0) scores[b * SEQ + s0 + wid + 4 * i] = sc;
        float mn = fmaxf(m, sc);
        float f = __expf(m - mn);
        float p = __expf(sc - mn);
        l = l * f + p;
#pragma unroll
        for (int j = 0; j < 4; ++j) {
            acc[j].x = fmaf(p, cur[j].x, acc[j].x * f);
            acc[j].y = fmaf(p, cur[j].y, acc[j].y * f);
            acc[j].z = fmaf(p, cur[j].z, acc[j].z * f);
            acc[j].w = fmaf(p, cur[j].w, acc[j].w * f);
        }
        m = mn;
    };

    step(bufA, bufB, 0);
    step(bufB, bufA, 1);
    step(bufA, bufB, 2);
    step(bufB, bufA, 3);
    step(bufA, bufB, 4);
    step(bufB, bufA, 5);
    step(bufA, bufB, 6);
    step(bufB, bufA, 7);

    // combine the 4 waves
    __shared__ float sacc[4][HIDDEN];
    __shared__ float sm[4], sl[4];
#pragma unroll
    for (int j = 0; j < 4; ++j)
        *(float4*)&sacc[wid][j * 256 + lane * 4] = acc[j];
    if (lane == 0) { sm[wid] = m; sl[wid] = l; }
    __syncthreads();
    float M = fmaxf(fmaxf(sm[0], sm[1]), fmaxf(sm[2], sm[3]));
    float f0 = __expf(sm[0] - M), f1 = __expf(sm[1] - M);
    float f2 = __expf(sm[2] - M), f3 = __expf(sm[3] - M);
    float L = sl[0] * f0 + sl[1] * f1 + sl[2] * f2 + sl[3] * f3;
    int h = threadIdx.x << 2;
    float4 a0 = *(const float4*)&sacc[0][h];
    float4 a1 = *(const float4*)&sacc[1][h];
    float4 a2 = *(const float4*)&sacc[2][h];
    float4 a3 = *(const float4*)&sacc[3][h];
    float4 r;
    r.x = a0.x * f0 + a1.x * f1 + a2.x * f2 + a3.x * f3;
    r.y = a0.y * f0 + a1.y * f1 + a2.y * f2 + a3.y * f3;
    r.z = a0.z * f0 + a1.z * f1 + a2.z * f2 + a3.z * f3;
    r.w = a0.w * f0 + a1.w * f1 + a2.w * f2 + a3.w * f3;
    *(float4*)&bacc[((size_t)blk << 10) + h] = r;
    if (threadIdx.x == 0) { bml[blk * 2] = M; bml[blk * 2 + 1] = L; }
}

// Per-batch combine: global (M,L), xb[b] = sum_i f_i*acc_i / L, normalize weights.
__global__ __launch_bounds__(256) void k_finalize(const float* __restrict__ bacc,
                                                  const float* __restrict__ bml,
                                                  float* __restrict__ weights,
                                                  float* __restrict__ xb) {
    int b = blockIdx.x;
    float M = -1e30f;
#pragma unroll
    for (int i = 0; i < NCHUNK; ++i) M = fmaxf(M, bml[(b * NCHUNK + i) * 2]);
    float L = 0.f;
    __shared__ float fs[NCHUNK];
#pragma unroll
    for (int i = 0; i < NCHUNK; ++i) {
        float f = __expf(bml[(b * NCHUNK + i) * 2] - M);
        L += f * bml[(b * NCHUNK + i) * 2 + 1];
        if (threadIdx.x == 0) fs[i] = f;
    }
    float invL = 1.f / L;
    __syncthreads();
    int h = threadIdx.x << 2;
    float4 r = make_float4(0.f, 0.f, 0.f, 0.f);
#pragma unroll
    for (int i = 0; i < NCHUNK; ++i) {
        float4 a = *(const float4*)&bacc[((size_t)(b * NCHUNK + i) << 10) + h];
        float f = fs[i] * invL;
        r.x = fmaf(f, a.x, r.x); r.y = fmaf(f, a.y, r.y);
        r.z = fmaf(f, a.z, r.z); r.w = fmaf(f, a.w, r.w);
    }
    *(float4*)&xb[(b << 10) + h] = r;
#pragma unroll
    for (int i = 0; i < SEQ / 256; ++i) {
        int s = threadIdx.x + i * 256;
        float sc = weights[b * SEQ + s];
        weights[b * SEQ + s] = __expf(sc - M) * invL;
    }
}

extern "C" void kernel_launch(void* const* d_in, const int* in_sizes, int n_in,
                              void* d_out, int out_size, void* d_ws, size_t ws_size,
                              hipStream_t stream) {
    const float* x  = (const float*)d_in[0];
    const float* Wq = (const float*)d_in[1];
    const float* bq = (const float*)d_in[2];
    const float* Wk = (const float*)d_in[3];
    const float* bk = (const float*)d_in[4];
    const float* Wv = (const float*)d_in[5];
    const float* bv = (const float*)d_in[6];

    float* out = (float*)d_out;
    float* ctx = out;                        // [B][H]
    float* wts = out + BATCH * HIDDEN;       // [B][S]

    float* ws   = (float*)d_ws;
    float* q    = ws;                        // B*H
    float* qk   = q + BATCH * HIDDEN;        // B*H
    float* cb   = qk + BATCH * HIDDEN;       // B (padded to 64)
    float* xb   = cb + 64;                   // B*H
    float* bml  = xb + BATCH * HIDDEN;       // B*NCHUNK*2
    float* bacc = bml + 2 * BATCH * NCHUNK;  // B*NCHUNK*H  (8 MiB)

    // q[b] = Wq x_last[b] + bq
    k_matvec<<<dim3((BATCH * HIDDEN) / 4), dim3(256), 0, stream>>>(
        Wq, x + (size_t)(SEQ - 1) * HIDDEN, (size_t)SEQ * HIDDEN, bq, q);
    // c[b] = q.bk / 32
    k_c<<<dim3(BATCH), dim3(64), 0, stream>>>(q, bk, cb);
    // qk[b] = Wk^T q[b] / 32
    k_qk<<<dim3(BATCH * 4), dim3(1024), 0, stream>>>(Wk, q, qk);
    // single pass over x: scores + online-softmax weighted accumulation
    k_attn<<<dim3(BATCH * NCHUNK), dim3(256), 0, stream>>>(x, qk, cb, wts, bacc, bml);
    // combine per-batch, write normalized weights + xb
    k_finalize<<<dim3(BATCH), dim3(256), 0, stream>>>(bacc, bml, wts, xb);
    // context[b] = Wv xb[b] + bv
    k_matvec<<<dim3((BATCH * HIDDEN) / 4), dim3(256), 0, stream>>>(
        Wv, xb, (size_t)HIDDEN, bv, ctx);
}

// Round 8
// 425.098 us; speedup vs baseline: 1.0902x; 1.0079x over previous
//
#include <hip/hip_runtime.h>

#define HIDDEN 1024
#define BATCH 32
#define SEQ 2048
#define NCHUNK 64
#define CHUNK 32  // SEQ / NCHUNK

__device__ __forceinline__ float wave_sum(float v) {
#pragma unroll
    for (int off = 32; off > 0; off >>= 1) v += __shfl_xor(v, off, 64);
    return v;
}

__device__ __forceinline__ float dot4(float4 a, float4 b) {
    return a.x * b.x + a.y * b.y + a.z * b.z + a.w * b.w;
}

// y[b][d] = dot(W[d,:], vin[b*vstride : +H]) + bias[d].  One wave per (b,d).
__global__ __launch_bounds__(256) void k_matvec(const float* __restrict__ W,
                                                const float* __restrict__ vin,
                                                size_t vstride,
                                                const float* __restrict__ bias,
                                                float* __restrict__ y) {
    int wave = blockIdx.x * 4 + (threadIdx.x >> 6);
    int lane = threadIdx.x & 63;
    int b = wave >> 10;
    int d = wave & 1023;
    const float* vr = vin + (size_t)b * vstride;
    const float* wr = W + ((size_t)d << 10);
    float acc = 0.f;
#pragma unroll
    for (int j = 0; j < 4; ++j)
        acc += dot4(*(const float4*)(vr + j * 256 + lane * 4),
                    *(const float4*)(wr + j * 256 + lane * 4));
    acc = wave_sum(acc);
    if (lane == 0) y[wave] = acc + bias[d];
}

// qk[b][h] = (sum_d Wk[d][h] * q[b][d]) / 32.  Block = 1024 threads:
// h = tid&255 (within the block's 256-h slab), dc = tid>>8 splits the d-loop
// 4 ways (16 waves/block for latency hiding); LDS combine at the end.
// NOTE: the reference's q.bk/32 score offset is constant over s within a batch;
// softmax is shift-invariant, so it cancels exactly in weights/context and is
// deliberately NOT computed (k_c kernel deleted).
__global__ __launch_bounds__(1024) void k_qk(const float* __restrict__ Wk,
                                             const float* __restrict__ q,
                                             float* __restrict__ qk) {
    int b = blockIdx.x >> 2;
    int hlo = threadIdx.x & 255;
    int h = ((blockIdx.x & 3) << 8) | hlo;
    int dc = threadIdx.x >> 8;  // 0..3
    const float* qr = q + (b << 10) + (dc << 8);
    const float* wp = Wk + (((size_t)dc << 8) << 10) + h;
    float a0 = 0.f, a1 = 0.f;
#pragma unroll 4
    for (int d = 0; d < 256; d += 2) {
        a0 = fmaf(wp[(size_t)d << 10], qr[d], a0);
        a1 = fmaf(wp[(size_t)(d + 1) << 10], qr[d + 1], a1);
    }
    __shared__ float red[4][256];
    red[dc][hlo] = a0 + a1;
    __syncthreads();
    if (threadIdx.x < 256) {
        float s = red[0][threadIdx.x] + red[1][threadIdx.x] +
                  red[2][threadIdx.x] + red[3][threadIdx.x];
        qk[(b << 10) | h] = s * (1.0f / 32.0f);
    }
}

// Fused flash-style pass: scores + online softmax + weighted-x accumulation.
// One block per (b, s-chunk of 32 rows). 4 waves; wave wid owns rows wid+4i.
// Row loads are double-buffered so iteration i+1's HBM load overlaps i's compute.
__global__ __launch_bounds__(256) void k_attn(const float* __restrict__ x,
                                              const float* __restrict__ qk,
                                              float* __restrict__ scores,   // raw (shifted) scores -> d_out weights area
                                              float* __restrict__ bacc,     // [B*NCHUNK][HIDDEN]
                                              float* __restrict__ bml) {    // [B*NCHUNK][2] = (m, l)
    int blk = blockIdx.x;
    int b = blk >> 6;
    int s0 = (blk & 63) * CHUNK;
    int wid = threadIdx.x >> 6, lane = threadIdx.x & 63;

    const float* qkr = qk + (b << 10);
    float4 qv[4];
#pragma unroll
    for (int j = 0; j < 4; ++j) qv[j] = *(const float4*)(qkr + j * 256 + lane * 4);

    float m = -1e30f, l = 0.f;
    float4 acc[4];
#pragma unroll
    for (int j = 0; j < 4; ++j) acc[j] = make_float4(0.f, 0.f, 0.f, 0.f);

    // base row for this wave: s0 + wid, stride 4 rows per iteration, 8 iterations
    const float* xr = x + ((size_t)b * SEQ + s0 + wid) * HIDDEN + lane * 4;

    float4 bufA[4], bufB[4];
#pragma unroll
    for (int j = 0; j < 4; ++j) bufA[j] = *(const float4*)(xr + j * 256);

    auto step = [&](float4 (&cur)[4], float4 (&nxt)[4], int i) {
        if (i < 7) {
            const float* xn = xr + (size_t)(i + 1) * 4 * HIDDEN;
#pragma unroll
            for (int j = 0; j < 4; ++j) nxt[j] = *(const float4*)(xn + j * 256);
        }
        float dt = 0.f;
#pragma unroll
        for (int j = 0; j < 4; ++j) dt += dot4(cur[j], qv[j]);
        float sc = wave_sum(dt);
        if (lane == 0) scores[b * SEQ + s0 + wid + 4 * i] = sc;
        float mn = fmaxf(m, sc);
        float f = __expf(m - mn);
        float p = __expf(sc - mn);
        l = l * f + p;
#pragma unroll
        for (int j = 0; j < 4; ++j) {
            acc[j].x = fmaf(p, cur[j].x, acc[j].x * f);
            acc[j].y = fmaf(p, cur[j].y, acc[j].y * f);
            acc[j].z = fmaf(p, cur[j].z, acc[j].z * f);
            acc[j].w = fmaf(p, cur[j].w, acc[j].w * f);
        }
        m = mn;
    };

    step(bufA, bufB, 0);
    step(bufB, bufA, 1);
    step(bufA, bufB, 2);
    step(bufB, bufA, 3);
    step(bufA, bufB, 4);
    step(bufB, bufA, 5);
    step(bufA, bufB, 6);
    step(bufB, bufA, 7);

    // combine the 4 waves
    __shared__ float sacc[4][HIDDEN];
    __shared__ float sm[4], sl[4];
#pragma unroll
    for (int j = 0; j < 4; ++j)
        *(float4*)&sacc[wid][j * 256 + lane * 4] = acc[j];
    if (lane == 0) { sm[wid] = m; sl[wid] = l; }
    __syncthreads();
    float M = fmaxf(fmaxf(sm[0], sm[1]), fmaxf(sm[2], sm[3]));
    float f0 = __expf(sm[0] - M), f1 = __expf(sm[1] - M);
    float f2 = __expf(sm[2] - M), f3 = __expf(sm[3] - M);
    float L = sl[0] * f0 + sl[1] * f1 + sl[2] * f2 + sl[3] * f3;
    int h = threadIdx.x << 2;
    float4 a0 = *(const float4*)&sacc[0][h];
    float4 a1 = *(const float4*)&sacc[1][h];
    float4 a2 = *(const float4*)&sacc[2][h];
    float4 a3 = *(const float4*)&sacc[3][h];
    float4 r;
    r.x = a0.x * f0 + a1.x * f1 + a2.x * f2 + a3.x * f3;
    r.y = a0.y * f0 + a1.y * f1 + a2.y * f2 + a3.y * f3;
    r.z = a0.z * f0 + a1.z * f1 + a2.z * f2 + a3.z * f3;
    r.w = a0.w * f0 + a1.w * f1 + a2.w * f2 + a3.w * f3;
    *(float4*)&bacc[((size_t)blk << 10) + h] = r;
    if (threadIdx.x == 0) { bml[blk * 2] = M; bml[blk * 2 + 1] = L; }
}

// Per-batch combine: global (M,L), xb[b] = sum_i f_i*acc_i / L, normalize weights.
__global__ __launch_bounds__(256) void k_finalize(const float* __restrict__ bacc,
                                                  const float* __restrict__ bml,
                                                  float* __restrict__ weights,
                                                  float* __restrict__ xb) {
    int b = blockIdx.x;
    float M = -1e30f;
#pragma unroll
    for (int i = 0; i < NCHUNK; ++i) M = fmaxf(M, bml[(b * NCHUNK + i) * 2]);
    float L = 0.f;
    __shared__ float fs[NCHUNK];
#pragma unroll
    for (int i = 0; i < NCHUNK; ++i) {
        float f = __expf(bml[(b * NCHUNK + i) * 2] - M);
        L += f * bml[(b * NCHUNK + i) * 2 + 1];
        if (threadIdx.x == 0) fs[i] = f;
    }
    float invL = 1.f / L;
    __syncthreads();
    int h = threadIdx.x << 2;
    float4 r = make_float4(0.f, 0.f, 0.f, 0.f);
#pragma unroll
    for (int i = 0; i < NCHUNK; ++i) {
        float4 a = *(const float4*)&bacc[((size_t)(b * NCHUNK + i) << 10) + h];
        float f = fs[i] * invL;
        r.x = fmaf(f, a.x, r.x); r.y = fmaf(f, a.y, r.y);
        r.z = fmaf(f, a.z, r.z); r.w = fmaf(f, a.w, r.w);
    }
    *(float4*)&xb[(b << 10) + h] = r;
#pragma unroll
    for (int i = 0; i < SEQ / 256; ++i) {
        int s = threadIdx.x + i * 256;
        float sc = weights[b * SEQ + s];
        weights[b * SEQ + s] = __expf(sc - M) * invL;
    }
}

extern "C" void kernel_launch(void* const* d_in, const int* in_sizes, int n_in,
                              void* d_out, int out_size, void* d_ws, size_t ws_size,
                              hipStream_t stream) {
    const float* x  = (const float*)d_in[0];
    const float* Wq = (const float*)d_in[1];
    const float* bq = (const float*)d_in[2];
    const float* Wk = (const float*)d_in[3];
    const float* bv = (const float*)d_in[6];
    const float* Wv = (const float*)d_in[5];
    // d_in[4] (bk) intentionally unused: its score contribution is constant
    // per batch and cancels in softmax (shift invariance).

    float* out = (float*)d_out;
    float* ctx = out;                        // [B][H]
    float* wts = out + BATCH * HIDDEN;       // [B][S]

    float* ws   = (float*)d_ws;
    float* q    = ws;                        // B*H
    float* qk   = q + BATCH * HIDDEN;        // B*H
    float* xb   = qk + BATCH * HIDDEN;       // B*H
    float* bml  = xb + BATCH * HIDDEN;       // B*NCHUNK*2
    float* bacc = bml + 2 * BATCH * NCHUNK;  // B*NCHUNK*H  (8 MiB)

    // q[b] = Wq x_last[b] + bq
    k_matvec<<<dim3((BATCH * HIDDEN) / 4), dim3(256), 0, stream>>>(
        Wq, x + (size_t)(SEQ - 1) * HIDDEN, (size_t)SEQ * HIDDEN, bq, q);
    // qk[b] = Wk^T q[b] / 32
    k_qk<<<dim3(BATCH * 4), dim3(1024), 0, stream>>>(Wk, q, qk);
    // single pass over x: scores + online-softmax weighted accumulation
    k_attn<<<dim3(BATCH * NCHUNK), dim3(256), 0, stream>>>(x, qk, wts, bacc, bml);
    // combine per-batch, write normalized weights + xb
    k_finalize<<<dim3(BATCH), dim3(256), 0, stream>>>(bacc, bml, wts, xb);
    // context[b] = Wv xb[b] + bv
    k_matvec<<<dim3((BATCH * HIDDEN) / 4), dim3(256), 0, stream>>>(
        Wv, xb, (size_t)HIDDEN, bv, ctx);
}